// Round 15
// baseline (151.492 us; speedup 1.0000x reference)
//
#include <hip/hip_runtime.h>
#include <hip/hip_bf16.h>

// Problem constants (B=2, N=2048, DIM=1024, H=16, HD=64, BS=64, M=32)
#define BB 2
#define NN 2048
#define DIMD 1024
#define HH 16
#define HD64 64
#define MB 32
#define SCALE_F 0.125f   // HD^-0.5

typedef __attribute__((ext_vector_type(8))) short bf16x8;
typedef __attribute__((ext_vector_type(8))) short short8v;
typedef __attribute__((ext_vector_type(4))) float f32x4;
typedef _Float16 f16;
typedef __attribute__((ext_vector_type(8))) _Float16 f16x8;
typedef __attribute__((ext_vector_type(4))) _Float16 f16x4;

// counted-vmcnt barrier discipline (T4) — GEMMs only (attn is barrier-free).
#define VM_WAIT8 asm volatile("s_waitcnt vmcnt(8)" ::: "memory")
#define VM_WAIT6 asm volatile("s_waitcnt vmcnt(6)" ::: "memory")
#define VM_WAIT0 asm volatile("s_waitcnt vmcnt(0)" ::: "memory")
#define SBAR __builtin_amdgcn_s_barrier()
#define SCHED0 __builtin_amdgcn_sched_barrier(0)

__device__ __forceinline__ unsigned short bf16_hi(float f) {
    return __builtin_bit_cast(unsigned short, __float2bfloat16(f));
}
__device__ __forceinline__ float bf16_val(unsigned short u) {
    return __bfloat162float(__builtin_bit_cast(__hip_bfloat16, u));
}
__device__ __forceinline__ short f16_bits(float f) {
    return __builtin_bit_cast(short, (f16)f);
}
__device__ __forceinline__ void async_copy16(const void* g, void* l) {
    __builtin_amdgcn_global_load_lds((const __attribute__((address_space(1))) void*)g,
                                     (__attribute__((address_space(3))) void*)l, 16, 0, 0);
}

// ===========================================================================
// FAST PATH — single-product f16 (R8), in-kernel mask (R11), swapped-operand
// softmax (R12), BK=64 GEMMs (R13), Q-in-regs (R14). R15: BARRIER-FREE attn —
// K/V fragments read directly from the L2-resident images (same byte offsets
// the LDS path used; images are XCD-local via block swizzle). No shared LDS
// state -> no barriers, no vmcnt discipline; waves fully independent.
// Values and FP order unchanged -> bit-identical output.
// ===========================================================================

// Fused input split: [0,4096) x -> Axs; [4096,7168) qkv_w -> Wqs;
// [7168,8192) proj_w -> Wp.  Single-plane f16.
__global__ __launch_bounds__(256) void split_in_fused_kernel(
    const float* __restrict__ x, short* __restrict__ Axs,
    const float* __restrict__ w, short* __restrict__ Wqs,
    const float* __restrict__ pw, short* __restrict__ Wp)
{
    const int bid = blockIdx.x;
    const float* src; short* dst; int idx;
    if (bid < 4096)      { src = x;  dst = Axs; idx = bid * 256 + threadIdx.x; }
    else if (bid < 7168) { src = w;  dst = Wqs; idx = (bid - 4096) * 256 + threadIdx.x; }
    else                 { src = pw; dst = Wp;  idx = (bid - 7168) * 256 + threadIdx.x; }
    int e = idx * 4;
    float4 v = *(const float4*)(src + e);
    ushort4 o = make_ushort4((unsigned short)f16_bits(v.x), (unsigned short)f16_bits(v.y),
                             (unsigned short)f16_bits(v.z), (unsigned short)f16_bits(v.w));
    *(ushort4*)(dst + e) = o;
}

// QKV GEMM, f16 single-product — R13 VERBATIM (BK=64, vmcnt(8), 32 MFMA/pair).
// Epilogue writes producer-formatted f16 images + fused block-mean.
__global__ __launch_bounds__(256) void qkv_mfma_kernel(
    const short* __restrict__ A, const short* __restrict__ W,
    short* __restrict__ QhI, short* __restrict__ KhI, short* __restrict__ VtI,
    float* __restrict__ qbf, float* __restrict__ kbf)
{
    __shared__ short SM[32768];   // A: 2 bufs x 2 subs x 4096 | W same = 64 KB
    const int wg = blockIdx.x;
    const int row0 = (wg / 24) * 128;
    const int col0 = (wg % 24) * 128;
    const int tid = threadIdx.x;
    const int lane = tid & 63;
    const int wave = tid >> 6;
    const int wm = wave & 1, wn = wave >> 1;

    auto AHS = [&](int b) { return SM + b * 8192; };           // 2 subs x 4096
    auto WHS = [&](int b) { return SM + 16384 + b * 8192; };

    f32x4 acc[4][4];
    const f32x4 zero = {0.f, 0.f, 0.f, 0.f};
    #pragma unroll
    for (int i = 0; i < 4; ++i)
        #pragma unroll
        for (int j = 0; j < 4; ++j) acc[i][j] = zero;

    const int ldr = lane >> 2;                              // row in 16-row chunk
    const int lko = (((lane & 3) ^ ((lane >> 3) & 3))) * 8; // swizzled k-chunk
    const int rsl = ((lane >> 4) ^ ((lane >> 1) & 3)) * 8;  // frag-read slot

    // 8 global_load_lds per wave per call (2 chunks x 2 subs x {A,W})
    auto stage = [&](int bufi, int ktn) {
        const int kk = ktn << 6;                            // 64 k per step
        #pragma unroll
        for (int i = 0; i < 2; ++i) {
            const int chunk = wave * 2 + i;
            #pragma unroll
            for (int sub = 0; sub < 2; ++sub) {
                const short* gA = A + (size_t)(row0 + chunk * 16 + ldr) * 1024 + kk + sub * 32 + lko;
                const short* gW = W + (size_t)(col0 + chunk * 16 + ldr) * 1024 + kk + sub * 32 + lko;
                async_copy16(gA, (char*)AHS(bufi) + sub * 8192 + chunk * 1024);
                async_copy16(gW, (char*)WHS(bufi) + sub * 8192 + chunk * 1024);
            }
        }
    };

    auto compute = [&](int bufi) {
        #pragma unroll
        for (int sub = 0; sub < 2; ++sub) {
            const short* Ah = AHS(bufi) + sub * 4096;
            const short* Wh = WHS(bufi) + sub * 4096;
            f16x8 ah[4], wh[4];
            #pragma unroll
            for (int mi = 0; mi < 4; ++mi)
                ah[mi] = *(const f16x8*)(Ah + (wm * 64 + mi * 16 + (lane & 15)) * 32 + rsl);
            #pragma unroll
            for (int ni = 0; ni < 4; ++ni)
                wh[ni] = *(const f16x8*)(Wh + (wn * 64 + ni * 16 + (lane & 15)) * 32 + rsl);
            #pragma unroll
            for (int mi = 0; mi < 4; ++mi)
                #pragma unroll
                for (int ni = 0; ni < 4; ++ni)
                    acc[mi][ni] = __builtin_amdgcn_mfma_f32_16x16x32_f16(ah[mi], wh[ni], acc[mi][ni], 0, 0, 0);
        }
    };

    // 16 k-steps, 2-buf 1-ahead
    stage(0, 0);
    for (int kt = 0; kt < 14; kt += 2) {
        stage(1, kt + 1);
        VM_WAIT8; SBAR; SCHED0;
        compute(0);
        SBAR;
        stage(0, kt + 2);
        VM_WAIT8; SBAR; SCHED0;
        compute(1);
        SBAR;
    }
    stage(1, 15);
    VM_WAIT8; SBAR; SCHED0;
    compute(0);
    SBAR;
    VM_WAIT0; SBAR; SCHED0;
    compute(1);
    SBAR;   // protect LDS reuse by V-wave transpose below

    // ---- epilogue: write f16 image tiles (+ fused block-mean for q/k)
    const int gr_first = row0 + wm * 64;          // wave's 64-row token block
    const int bb = gr_first >> 11;
    const int mblk = (gr_first & 2047) >> 6;
    const int gc0 = col0 + wn * 64;               // wave's 64-col band (one head)
    const int tsel = gc0 >> 10;
    const int h = (gc0 >> 6) & 15;
    const int tile = ((bb << 4) + h) * 32 + mblk;
    const float sc = (tsel == 0) ? SCALE_F : 1.0f;

    if (tsel != 2) {
        short* baseH = ((tsel == 0) ? QhI : KhI) + (size_t)tile * 4096;
        float* mdst  = ((tsel == 0) ? qbf : kbf) + ((size_t)((bb << 4) + h) * 32 + mblk) * 64;
        #pragma unroll
        for (int ni = 0; ni < 4; ++ni) {
            const int d = ni * 16 + (lane & 15);
            float colsum = 0.f;
            #pragma unroll
            for (int mi = 0; mi < 4; ++mi) {
                #pragma unroll
                for (int r = 0; r < 4; ++r) {
                    const int row = mi * 16 + (lane >> 4) * 4 + r;
                    float v = acc[mi][ni][r] * sc;
                    colsum += v;
                    const int off = (row * 64 + d) ^ ((row & 7) << 3);   // shorts
                    baseH[off] = f16_bits(v);
                }
            }
            colsum += __shfl_xor(colsum, 16);
            colsum += __shfl_xor(colsum, 32);
            if ((lane >> 4) == 0) mdst[d] = colsum * (1.f / 64.f);
        }
    } else {
        // V: transpose 64x64 tile in per-wave LDS region, write Vt[d][kk] image
        short* tb = SM + wave * 4160;   // 64x65 shorts, per-wave exclusive
        #pragma unroll
        for (int ni = 0; ni < 4; ++ni)
            #pragma unroll
            for (int mi = 0; mi < 4; ++mi)
                #pragma unroll
                for (int r = 0; r < 4; ++r) {
                    const int row = mi * 16 + (lane >> 4) * 4 + r;   // kk
                    const int d = ni * 16 + (lane & 15);
                    tb[row * 65 + d] = f16_bits(acc[mi][ni][r]);
                }
        short* vout = VtI + (size_t)tile * 4096;
        #pragma unroll
        for (int c = 0; c < 8; ++c) {
            short8v tv;
            #pragma unroll
            for (int j = 0; j < 8; ++j)
                tv[j] = tb[(c * 8 + j) * 65 + lane];
            const int off = (lane * 64 + c * 8) ^ ((lane & 7) << 3);   // shorts
            *(short8v*)(vout + off) = tv;
        }
    }
}

// Block-scores + top-2 mask (FALLBACK PATH ONLY).
__global__ __launch_bounds__(256) void scores_splitw_kernel(
    const float* __restrict__ qbf, const float* __restrict__ kbf,
    unsigned int* __restrict__ maskbits, float scale,
    const float* __restrict__ projw, short* __restrict__ Wdst)
{
    __shared__ float qs_[32][64];
    __shared__ float ks_[32][64];
    __shared__ float cb[32][32];
    const int bid = blockIdx.x;
    const int tid = threadIdx.x;

    if (bid >= 32) {
        int idx = (bid - 32) * 256 + tid;
        int e = idx * 4;
        float4 v = *(const float4*)(projw + e);
        ushort4 o = make_ushort4((unsigned short)f16_bits(v.x), (unsigned short)f16_bits(v.y),
                                 (unsigned short)f16_bits(v.z), (unsigned short)f16_bits(v.w));
        *(ushort4*)(Wdst + e) = o;
        return;
    }

    #pragma unroll
    for (int i = 0; i < 8; ++i) {
        int e = tid + i * 256;
        qs_[e >> 6][e & 63] = qbf[(size_t)bid * 2048 + e];
        ks_[e >> 6][e & 63] = kbf[(size_t)bid * 2048 + e];
    }
    __syncthreads();

    #pragma unroll
    for (int i = 0; i < 4; ++i) {
        int idx = tid + i * 256;
        int r = idx >> 5, c = idx & 31;
        float s = 0.f;
        #pragma unroll
        for (int d = 0; d < 64; ++d) s += qs_[r][d] * ks_[c][d];
        cb[r][c] = s * scale;
    }
    __syncthreads();

    if (tid < 32) {
        float m1 = -INFINITY, m2 = -INFINITY;
        for (int n = 0; n < 32; ++n) {
            float v = cb[tid][n];
            if (v > m1) { m2 = m1; m1 = v; }
            else if (v > m2) { m2 = v; }
        }
        unsigned int bits = 1u << tid;
        for (int n = 0; n < 32; ++n)
            if (cb[tid][n] >= m2) bits |= 1u << n;
        maskbits[bid * 32 + tid] = bits;
    }
}

// Proj GEMM, f16 single-product + bias — R13 VERBATIM (BK=64, vmcnt(6)).
__global__ __launch_bounds__(256) void proj_mfma_kernel(
    const short* __restrict__ A, const short* __restrict__ W,
    const float* __restrict__ bias, float* __restrict__ out)
{
    __shared__ short Ahs[2][8192];   // 2 subs x 4096
    __shared__ short Whs[2][4096];   // 2 subs x 2048
    const int bid = blockIdx.x;
    const int wg = (bid & 7) * 64 + (bid >> 3);   // bijective (512 % 8 == 0)
    const int row0 = (wg >> 4) * 128;
    const int col0 = (wg & 15) * 64;
    const int tid = threadIdx.x;
    const int lane = tid & 63;
    const int wave = tid >> 6;

    f32x4 acc[2][4];
    const f32x4 zero = {0.f, 0.f, 0.f, 0.f};
    #pragma unroll
    for (int i = 0; i < 2; ++i)
        #pragma unroll
        for (int j = 0; j < 4; ++j) acc[i][j] = zero;

    const int ldr = lane >> 2;
    const int lko = (((lane & 3) ^ ((lane >> 3) & 3))) * 8;
    const int rsl = ((lane >> 4) ^ ((lane >> 1) & 3)) * 8;

    // 6 global_load_lds per wave per call (A: 2 chunks x 2 subs; W: 2 subs)
    auto stage = [&](int bufi, int ktn) {
        const int kk = ktn << 6;
        #pragma unroll
        for (int i = 0; i < 2; ++i) {
            const int chunk = wave * 2 + i;
            #pragma unroll
            for (int sub = 0; sub < 2; ++sub) {
                const short* gA = A + (size_t)(row0 + chunk * 16 + ldr) * 1024 + kk + sub * 32 + lko;
                async_copy16(gA, (char*)&Ahs[bufi][0] + sub * 8192 + chunk * 1024);
            }
        }
        #pragma unroll
        for (int sub = 0; sub < 2; ++sub) {
            const short* gW = W + (size_t)(col0 + wave * 16 + ldr) * 1024 + kk + sub * 32 + lko;
            async_copy16(gW, (char*)&Whs[bufi][0] + sub * 4096 + wave * 1024);
        }
    };

    auto compute = [&](int bufi) {
        #pragma unroll
        for (int sub = 0; sub < 2; ++sub) {
            const short* Ah = &Ahs[bufi][0] + sub * 4096;
            const short* Wh = &Whs[bufi][0] + sub * 2048;
            f16x8 ah[2], wh[4];
            #pragma unroll
            for (int mi = 0; mi < 2; ++mi)
                ah[mi] = *(const f16x8*)(Ah + (wave * 32 + mi * 16 + (lane & 15)) * 32 + rsl);
            #pragma unroll
            for (int ni = 0; ni < 4; ++ni)
                wh[ni] = *(const f16x8*)(Wh + (ni * 16 + (lane & 15)) * 32 + rsl);
            #pragma unroll
            for (int mi = 0; mi < 2; ++mi)
                #pragma unroll
                for (int ni = 0; ni < 4; ++ni)
                    acc[mi][ni] = __builtin_amdgcn_mfma_f32_16x16x32_f16(ah[mi], wh[ni], acc[mi][ni], 0, 0, 0);
        }
    };

    stage(0, 0);
    for (int kt = 0; kt < 14; kt += 2) {
        stage(1, kt + 1);
        VM_WAIT6; SBAR; SCHED0;
        compute(0);
        SBAR;
        stage(0, kt + 2);
        VM_WAIT6; SBAR; SCHED0;
        compute(1);
        SBAR;
    }
    stage(1, 15);
    VM_WAIT6; SBAR; SCHED0;
    compute(0);
    SBAR;
    VM_WAIT0; SBAR; SCHED0;
    compute(1);

    #pragma unroll
    for (int ni = 0; ni < 4; ++ni) {
        int gc = col0 + ni * 16 + (lane & 15);
        float bv = bias[gc];
        #pragma unroll
        for (int mi = 0; mi < 2; ++mi) {
            int gr0 = row0 + wave * 32 + mi * 16 + (lane >> 4) * 4;
            #pragma unroll
            for (int r = 0; r < 4; ++r)
                out[(size_t)(gr0 + r) * 1024 + gc] = acc[mi][ni][r] + bv;
        }
    }
}

// ---------------------------------------------------------------------------
// Sparse block attention — R15: BARRIER-FREE. K/V fragments read directly
// from the L2-resident images (identical byte offsets to the old LDS path;
// the LDS copy was layout-identical). Only Pb (wave-private) stays in LDS.
// No barriers, no vmcnt: waves run fully independently. Same tile order
// (diag first, then ascending bits) -> bit-identical output vs R14.
// ---------------------------------------------------------------------------
__global__ __launch_bounds__(256) void sparse_attn_mfma_kernel(
    const short* __restrict__ QhI, const short* __restrict__ KhI,
    const short* __restrict__ VtI,
    const float* __restrict__ qbf, const float* __restrict__ kbf,
    short* __restrict__ aout)
{
    __shared__ f16 Pb[4096];                  // P[q][kk], LSTR=64, XOR swizzled

    const int bid = blockIdx.x;
    const int wg = (bid & 7) * 128 + (bid >> 3);  // bijective (1024 % 8 == 0)
    const int m  = wg & 31;
    const int bh = wg >> 5;
    const int b  = bh >> 4, h = bh & 15;
    const int tid = threadIdx.x;
    const int lane = tid & 63;
    const int wave = tid >> 6;
    const f32x4 zero = {0.f, 0.f, 0.f, 0.f};

    const int arow = wave * 16 + (lane & 15);
    const int kofs = (lane >> 4) * 8;      // shorts (for Pb)
    const int colb = (lane >> 4) * 16;     // bytes (for swizzled images)
    const int pswz = (arow & 7) << 3;      // Pb XOR (shorts)

    // ---- Q fragment to REGISTERS (same swizzled image offsets)
    f16x8 qreg[2];
    {
        const short* qt = QhI + (size_t)(bh * 32 + m) * 4096;
        #pragma unroll
        for (int c = 0; c < 2; ++c) {
            const int qoff = (arow * 128 + c * 64 + colb) ^ ((arow & 7) << 4);  // bytes
            qreg[c] = *(const f16x8*)((const char*)qt + qoff);
        }
    }

    // ---- in-kernel mask (R11-proven; FP order == old scores kernel)
    unsigned int mask;
    {
        float c = -INFINITY;
        if (lane < 32) {
            const float* qrow = qbf + ((size_t)bh * 32 + m) * 64;
            const float* krow = kbf + ((size_t)bh * 32 + lane) * 64;
            float s = 0.f;
            for (int d = 0; d < 64; ++d) s += qrow[d] * krow[d];
            c = s;
        }
        float m1 = c;
        #pragma unroll
        for (int off = 1; off < 64; off <<= 1) m1 = fmaxf(m1, __shfl_xor(m1, off));
        unsigned long long eq = __ballot(c == m1);
        float cx = (c == m1) ? -INFINITY : c;
        #pragma unroll
        for (int off = 1; off < 64; off <<= 1) cx = fmaxf(cx, __shfl_xor(cx, off));
        float m2 = (__popcll(eq) >= 2) ? m1 : cx;
        unsigned long long ge = __ballot(c >= m2);
        mask = (unsigned int)(ge & 0xffffffffULL) | (1u << m);
    }

    f32x4 o_acc[4];
    float macc_s = -INFINITY, lacc_s = 0.f;   // per-lane: q = wave*16+(lane&15)
    #pragma unroll
    for (int t = 0; t < 4; ++t) o_acc[t] = zero;

    auto computeTile = [&](int nb) {
        const size_t t4 = (size_t)(bh * 32 + nb) * 4096;
        const char* KhB = (const char*)(KhI + t4);
        const char* VtB = (const char*)(VtI + t4);
        // ---- QK^T, SWAPPED operands: mfma(K, Q) -> D[k_local][q]
        f32x4 s_acc[4];
        #pragma unroll
        for (int t = 0; t < 4; ++t) s_acc[t] = zero;
        #pragma unroll
        for (int c = 0; c < 2; ++c) {
            #pragma unroll
            for (int t = 0; t < 4; ++t) {
                const int krow = t * 16 + (lane & 15);
                const int koff = (krow * 128 + c * 64 + colb) ^ ((krow & 7) << 4);
                f16x8 bh_ = *(const f16x8*)(KhB + koff);
                s_acc[t] = __builtin_amdgcn_mfma_f32_16x16x32_f16(bh_, qreg[c], s_acc[t], 0, 0, 0);
            }
        }

        // ---- per-lane online softmax (q = arow)
        float vmax = s_acc[0][0];
        #pragma unroll
        for (int t = 0; t < 4; ++t)
            #pragma unroll
            for (int r = 0; r < 4; ++r) vmax = fmaxf(vmax, s_acc[t][r]);
        vmax = fmaxf(vmax, __shfl_xor(vmax, 16));
        vmax = fmaxf(vmax, __shfl_xor(vmax, 32));
        float mnew = fmaxf(macc_s, vmax);
        float alpha = expf(macc_s - mnew);
        macc_s = mnew;

        float psum = 0.f;
        #pragma unroll
        for (int t = 0; t < 4; ++t) {
            f16x4 pv;
            #pragma unroll
            for (int r = 0; r < 4; ++r) {
                float p = expf(s_acc[t][r] - mnew);
                psum += p;
                pv[r] = (f16)p;
            }
            // k = t*16 + (lane>>4)*4 + r; XOR flips bits 3-5 only (row-local)
            *(f16x4*)(Pb + ((arow * 64 + t * 16 + (lane >> 4) * 4) ^ pswz)) = pv;
        }
        psum += __shfl_xor(psum, 16);
        psum += __shfl_xor(psum, 32);
        lacc_s = lacc_s * alpha + psum;

        float ab[4];
        #pragma unroll
        for (int r = 0; r < 4; ++r) ab[r] = __shfl(alpha, (lane >> 4) * 4 + r);
        #pragma unroll
        for (int t = 0; t < 4; ++t)
            #pragma unroll
            for (int r = 0; r < 4; ++r) o_acc[t][r] *= ab[r];

        // ---- PV (Pb rows wave-private; same XOR on read; in-wave ds
        // write->read ordering is compiler-handled via lgkmcnt)
        #pragma unroll
        for (int c = 0; c < 2; ++c) {
            f16x8 af = *(const f16x8*)(Pb + ((arow * 64 + c * 32 + kofs) ^ pswz));
            #pragma unroll
            for (int t = 0; t < 4; ++t) {
                const int vrow = t * 16 + (lane & 15);
                const int voff = (vrow * 128 + c * 64 + colb) ^ ((vrow & 7) << 4);
                f16x8 bf = *(const f16x8*)(VtB + voff);
                o_acc[t] = __builtin_amdgcn_mfma_f32_16x16x32_f16(af, bf, o_acc[t], 0, 0, 0);
            }
        }
    };

    // ---- masked loop: diagonal first, then remaining set bits ascending
    // (same order as R14 -> identical FP accumulation).
    computeTile(m);
    unsigned int mm = mask & ~(1u << m);
    while (mm) {
        int nb = __builtin_ctz(mm); mm &= mm - 1;
        computeTile(nb);
    }

    // ---- epilogue: normalize (broadcast inv to o_acc rows), write f16 out
    float inv_s = (lacc_s > 0.f) ? (1.f / lacc_s) : 0.f;
    float invb[4];
    #pragma unroll
    for (int r = 0; r < 4; ++r) invb[r] = __shfl(inv_s, (lane >> 4) * 4 + r);
    #pragma unroll
    for (int t = 0; t < 4; ++t) {
        int gc = h * 64 + t * 16 + (lane & 15);
        #pragma unroll
        for (int r = 0; r < 4; ++r) {
            int grow = b * NN + m * 64 + wave * 16 + (lane >> 4) * 4 + r;
            float v = o_acc[t][r] * invb[r];
            aout[(size_t)grow * 1024 + gc] = f16_bits(v);
        }
    }
}

// ===========================================================================
// FALLBACK KERNELS (round-2 proven fp32 path)
// ===========================================================================

__global__ __launch_bounds__(256) void block_mean_kernel(
    const float* __restrict__ qf, const float* __restrict__ kf,
    float* __restrict__ qbf, float* __restrict__ kbf)
{
    int idx = blockIdx.x * 256 + threadIdx.x;
    const float* src = (idx < 65536) ? qf : kf;
    float* dst       = (idx < 65536) ? qbf : kbf;
    int e = idx & 65535;
    int d = e & 63;
    int r = e >> 6;
    size_t base = (size_t)r * 4096 + d;
    float s = 0.f;
    #pragma unroll
    for (int i = 0; i < 64; ++i) s += src[base + (size_t)i * 64];
    dst[e] = s * (1.f / 64.f);
}

__global__ __launch_bounds__(256) void qkv_gemm_fb(
    const float* __restrict__ x, const float* __restrict__ w,
    float* __restrict__ qf, float* __restrict__ kf, float* __restrict__ vf)
{
    __shared__ float As[64][33];
    __shared__ float Bs[64][33];
    const int tid = threadIdx.x;
    const int row0 = blockIdx.y * 64;
    const int col0 = blockIdx.x * 64;
    const int ty = tid >> 4, tx = tid & 15;

    float acc[4][4] = {};
    for (int k0 = 0; k0 < 1024; k0 += 32) {
        #pragma unroll
        for (int i = 0; i < 8; ++i) {
            int e = tid + i * 256;
            int r = e >> 5, c = e & 31;
            As[r][c] = x[(size_t)(row0 + r) * 1024 + k0 + c];
            Bs[r][c] = w[(size_t)(col0 + r) * 1024 + k0 + c];
        }
        __syncthreads();
        #pragma unroll
        for (int kk = 0; kk < 32; ++kk) {
            float a[4], bq[4];
            #pragma unroll
            for (int i = 0; i < 4; ++i) a[i] = As[ty * 4 + i][kk];
            #pragma unroll
            for (int j = 0; j < 4; ++j) bq[j] = Bs[tx * 4 + j][kk];
            #pragma unroll
            for (int i = 0; i < 4; ++i)
                #pragma unroll
                for (int j = 0; j < 4; ++j)
                    acc[i][j] += a[i] * bq[j];
        }
        __syncthreads();
    }

    const int tsel = col0 >> 10;
    const int h    = (col0 & 1023) >> 6;
    float* dstbuf = (tsel == 0) ? qf : (tsel == 1) ? kf : vf;
    #pragma unroll
    for (int i = 0; i < 4; ++i) {
        int row = row0 + ty * 4 + i;
        int b   = row >> 11, n = row & 2047;
        size_t rb = ((size_t)(b * HH + h) * NN + n) * HD64;
        #pragma unroll
        for (int j = 0; j < 4; ++j)
            dstbuf[rb + tx * 4 + j] = acc[i][j];
    }
}

__global__ __launch_bounds__(256) void proj_gemm_fb(
    const float* __restrict__ attn, const float* __restrict__ w,
    const float* __restrict__ bias, float* __restrict__ out)
{
    __shared__ float As[64][33];
    __shared__ float Bs[64][33];
    const int tid = threadIdx.x;
    const int row0 = blockIdx.y * 64;
    const int col0 = blockIdx.x * 64;
    const int ty = tid >> 4, tx = tid & 15;

    float acc[4][4] = {};
    for (int k0 = 0; k0 < 1024; k0 += 32) {
        #pragma unroll
        for (int i = 0; i < 8; ++i) {
            int e = tid + i * 256;
            int r = e >> 5, c = e & 31;
            As[r][c] = attn[(size_t)(row0 + r) * 1024 + k0 + c];
            Bs[r][c] = w[(size_t)(col0 + r) * 1024 + k0 + c];
        }
        __syncthreads();
        #pragma unroll
        for (int kk = 0; kk < 32; ++kk) {
            float a[4], bq[4];
            #pragma unroll
            for (int i = 0; i < 4; ++i) a[i] = As[ty * 4 + i][kk];
            #pragma unroll
            for (int j = 0; j < 4; ++j) bq[j] = Bs[tx * 4 + j][kk];
            #pragma unroll
            for (int i = 0; i < 4; ++i)
                #pragma unroll
                for (int j = 0; j < 4; ++j)
                    acc[i][j] += a[i] * bq[j];
        }
        __syncthreads();
    }

    #pragma unroll
    for (int j = 0; j < 4; ++j) {
        int col = col0 + tx * 4 + j;
        float bv = bias[col];
        #pragma unroll
        for (int i = 0; i < 4; ++i) {
            int row = row0 + ty * 4 + i;
            out[(size_t)row * 1024 + col] = acc[i][j] + bv;
        }
    }
}

__global__ __launch_bounds__(256) void sparse_attn_fb(
    const float* __restrict__ qf, const float* __restrict__ kf,
    const float* __restrict__ vf, const unsigned int* __restrict__ maskbits,
    float* __restrict__ attnf)
{
    __shared__ float kbuf[64][64];
    __shared__ float vbuf[64][64];
    __shared__ float sbuf[64][65];
    const int m  = blockIdx.x & 31;
    const int bh = blockIdx.x >> 5;
    const int b  = bh >> 4, h = bh & 15;
    const int t  = threadIdx.x;
    const int qr = t >> 2;
    const int dg = t & 3;
    const int d0 = dg * 16;

    float qreg[16];
    {
        const float* qp = qf + ((size_t)bh * NN + m * 64 + qr) * HD64 + d0;
        #pragma unroll
        for (int j = 0; j < 16; j += 4) {
            float4 v = *(const float4*)(qp + j);
            qreg[j] = v.x; qreg[j+1] = v.y; qreg[j+2] = v.z; qreg[j+3] = v.w;
        }
    }

    const unsigned int mask = maskbits[bh * 32 + m];
    float macc = -INFINITY, lacc = 0.f;
    float oacc[16];
    #pragma unroll
    for (int j = 0; j < 16; ++j) oacc[j] = 0.f;

    for (int nb = 0; nb < 32; ++nb) {
        if (!((mask >> nb) & 1u)) continue;
        __syncthreads();
        {
            const float* gk = kf + ((size_t)bh * NN + nb * 64) * HD64;
            const float* gv = vf + ((size_t)bh * NN + nb * 64) * HD64;
            #pragma unroll
            for (int i = 0; i < 4; ++i) {
                async_copy16(gk + t * 4 + i * 1024, (char*)kbuf + t * 16 + i * 4096);
                async_copy16(gv + t * 4 + i * 1024, (char*)vbuf + t * 16 + i * 4096);
            }
        }
        __syncthreads();

        float bmax = -INFINITY;
        for (int kk = 0; kk < 64; ++kk) {
            float s = 0.f;
            #pragma unroll
            for (int j = 0; j < 16; ++j) s += qreg[j] * kbuf[kk][d0 + j];
            s += __shfl_xor(s, 1);
            s += __shfl_xor(s, 2);
            s *= SCALE_F;
            if (dg == 0) sbuf[qr][kk] = s;
            bmax = fmaxf(bmax, s);
        }
        float mnew  = fmaxf(macc, bmax);
        float alpha = expf(macc - mnew);
        lacc *= alpha;
        #pragma unroll
        for (int j = 0; j < 16; ++j) oacc[j] *= alpha;
        for (int kk = 0; kk < 64; ++kk) {
            float p = expf(sbuf[qr][kk] - mnew);
            lacc += p;
            #pragma unroll
            for (int j = 0; j < 16; ++j) oacc[j] += p * vbuf[kk][d0 + j];
        }
        macc = mnew;
    }

    float inv = (lacc > 0.f) ? (1.f / lacc) : 0.f;
    size_t orow = ((size_t)(b * NN + m * 64 + qr)) * DIMD + h * 64 + d0;
    #pragma unroll
    for (int j = 0; j < 16; ++j) attnf[orow + j] = oacc[j] * inv;
}

// ---------------------------------------------------------------------------
extern "C" void kernel_launch(void* const* d_in, const int* in_sizes, int n_in,
                              void* d_out, int out_size, void* d_ws, size_t ws_size,
                              hipStream_t stream)
{
    const float* x      = (const float*)d_in[0];
    const float* qkv_w  = (const float*)d_in[1];
    const float* proj_w = (const float*)d_in[2];
    const float* proj_b = (const float*)d_in[3];
    float* out = (float*)d_out;

    // Carve (fast path, ~41 MB):
    //   Qh/Kh/Vt images: 3 x 8 MB f16 tiles [1024 tiles][4096 shorts]
    //   qbf/kbf 512K | mask 4K (fallback only)
    //   Axs 8M f16 [4096][1024] (x-split; reused as attention output)
    //   Wqs 6M f16 [3072][1024] | Wp 2M f16 [1024][1024]
    short* QhI = (short*)d_ws;
    short* KhI = QhI + 4194304;
    short* VtI = KhI + 4194304;
    float* qbf = (float*)(VtI + 4194304);
    float* kbf = qbf + 65536;
    unsigned int* maskb = (unsigned int*)(kbf + 65536);
    short* Axs = (short*)(maskb + 1024);
    short* Wqs = Axs + (size_t)4096 * 1024;
    short* Wp  = Wqs + (size_t)3072 * 1024;
    const size_t need_fast = (size_t)((char*)(Wp + (size_t)1024 * 1024) - (char*)d_ws);

    if (ws_size >= need_fast) {
        split_in_fused_kernel<<<8192, 256, 0, stream>>>(x, Axs, qkv_w, Wqs, proj_w, Wp);
        qkv_mfma_kernel<<<768, 256, 0, stream>>>(Axs, Wqs, QhI, KhI, VtI, qbf, kbf);
        sparse_attn_mfma_kernel<<<1024, 256, 0, stream>>>(QhI, KhI, VtI, qbf, kbf, Axs);
        proj_mfma_kernel<<<512, 256, 0, stream>>>(Axs, Wp, proj_b, out);
    } else {
        float* qf2  = (float*)d_ws;
        float* kf2  = qf2 + 4194304;
        float* vf2  = kf2 + 4194304;
        float* qbf2 = vf2 + 4194304;
        float* kbf2 = qbf2 + 65536;
        unsigned int* maskb2 = (unsigned int*)(kbf2 + 65536);
        float* attnf = (float*)(maskb2 + 1024);
        qkv_gemm_fb<<<dim3(48, 64), 256, 0, stream>>>(x, qkv_w, qf2, kf2, vf2);
        block_mean_kernel<<<512, 256, 0, stream>>>(qf2, kf2, qbf2, kbf2);
        scores_splitw_kernel<<<32, 256, 0, stream>>>(qbf2, kbf2, maskb2, SCALE_F,
                                                     (const float*)nullptr, (short*)nullptr);
        sparse_attn_fb<<<1024, 256, 0, stream>>>(qf2, kf2, vf2, maskb2, attnf);
        proj_gemm_fb<<<dim3(16, 64), 256, 0, stream>>>(attnf, proj_w, proj_b, out);
    }
}

// Round 16
// 147.740 us; speedup vs baseline: 1.0254x; 1.0254x over previous
//
#include <hip/hip_runtime.h>
#include <hip/hip_bf16.h>

// Problem constants (B=2, N=2048, DIM=1024, H=16, HD=64, BS=64, M=32)
#define BB 2
#define NN 2048
#define DIMD 1024
#define HH 16
#define HD64 64
#define MB 32
#define SCALE_F 0.125f   // HD^-0.5

typedef __attribute__((ext_vector_type(8))) short bf16x8;
typedef __attribute__((ext_vector_type(8))) short short8v;
typedef __attribute__((ext_vector_type(4))) float f32x4;
typedef _Float16 f16;
typedef __attribute__((ext_vector_type(8))) _Float16 f16x8;
typedef __attribute__((ext_vector_type(4))) _Float16 f16x4;

// counted-vmcnt barrier discipline (T4) — 2-buf 1-ahead, proven quanta:
// vmcnt(8) = qkv BK=64; vmcnt(6) = proj BK=64; vmcnt(4) = attn.
#define VM_WAIT8 asm volatile("s_waitcnt vmcnt(8)" ::: "memory")
#define VM_WAIT6 asm volatile("s_waitcnt vmcnt(6)" ::: "memory")
#define VM_WAIT4 asm volatile("s_waitcnt vmcnt(4)" ::: "memory")
#define VM_WAIT0 asm volatile("s_waitcnt vmcnt(0)" ::: "memory")
#define SBAR __builtin_amdgcn_s_barrier()
#define SCHED0 __builtin_amdgcn_sched_barrier(0)

__device__ __forceinline__ unsigned short bf16_hi(float f) {
    return __builtin_bit_cast(unsigned short, __float2bfloat16(f));
}
__device__ __forceinline__ float bf16_val(unsigned short u) {
    return __bfloat162float(__builtin_bit_cast(__hip_bfloat16, u));
}
__device__ __forceinline__ short f16_bits(float f) {
    return __builtin_bit_cast(short, (f16)f);
}
__device__ __forceinline__ void async_copy16(const void* g, void* l) {
    __builtin_amdgcn_global_load_lds((const __attribute__((address_space(1))) void*)g,
                                     (__attribute__((address_space(3))) void*)l, 16, 0, 0);
}

// ===========================================================================
// FAST PATH — single-product f16 (R8), in-kernel mask (R11), swapped-operand
// softmax (R12), BK=64 GEMMs (R13), attn LDS diet (R14: Q in registers,
// Pb LSTR=64 XOR-swizzled, 40 KB LDS -> 4 blocks/CU).
// R16: REVERT of R15's barrier-free attn (regressed +3.9 µs — direct L2
// reads put ~200cy latency on the MFMA critical path; staged LDS + counted
// vmcnt prefetch wins). This is the R14-proven optimum, resubmitted.
// ===========================================================================

// Fused input split: [0,4096) x -> Axs; [4096,7168) qkv_w -> Wqs;
// [7168,8192) proj_w -> Wp.  Single-plane f16.
__global__ __launch_bounds__(256) void split_in_fused_kernel(
    const float* __restrict__ x, short* __restrict__ Axs,
    const float* __restrict__ w, short* __restrict__ Wqs,
    const float* __restrict__ pw, short* __restrict__ Wp)
{
    const int bid = blockIdx.x;
    const float* src; short* dst; int idx;
    if (bid < 4096)      { src = x;  dst = Axs; idx = bid * 256 + threadIdx.x; }
    else if (bid < 7168) { src = w;  dst = Wqs; idx = (bid - 4096) * 256 + threadIdx.x; }
    else                 { src = pw; dst = Wp;  idx = (bid - 7168) * 256 + threadIdx.x; }
    int e = idx * 4;
    float4 v = *(const float4*)(src + e);
    ushort4 o = make_ushort4((unsigned short)f16_bits(v.x), (unsigned short)f16_bits(v.y),
                             (unsigned short)f16_bits(v.z), (unsigned short)f16_bits(v.w));
    *(ushort4*)(dst + e) = o;
}

// QKV GEMM, f16 single-product — R13 VERBATIM (BK=64, vmcnt(8), 32 MFMA/pair).
// Epilogue writes producer-formatted f16 images + fused block-mean.
__global__ __launch_bounds__(256) void qkv_mfma_kernel(
    const short* __restrict__ A, const short* __restrict__ W,
    short* __restrict__ QhI, short* __restrict__ KhI, short* __restrict__ VtI,
    float* __restrict__ qbf, float* __restrict__ kbf)
{
    __shared__ short SM[32768];   // A: 2 bufs x 2 subs x 4096 | W same = 64 KB
    const int wg = blockIdx.x;
    const int row0 = (wg / 24) * 128;
    const int col0 = (wg % 24) * 128;
    const int tid = threadIdx.x;
    const int lane = tid & 63;
    const int wave = tid >> 6;
    const int wm = wave & 1, wn = wave >> 1;

    auto AHS = [&](int b) { return SM + b * 8192; };           // 2 subs x 4096
    auto WHS = [&](int b) { return SM + 16384 + b * 8192; };

    f32x4 acc[4][4];
    const f32x4 zero = {0.f, 0.f, 0.f, 0.f};
    #pragma unroll
    for (int i = 0; i < 4; ++i)
        #pragma unroll
        for (int j = 0; j < 4; ++j) acc[i][j] = zero;

    const int ldr = lane >> 2;                              // row in 16-row chunk
    const int lko = (((lane & 3) ^ ((lane >> 3) & 3))) * 8; // swizzled k-chunk
    const int rsl = ((lane >> 4) ^ ((lane >> 1) & 3)) * 8;  // frag-read slot

    // 8 global_load_lds per wave per call (2 chunks x 2 subs x {A,W})
    auto stage = [&](int bufi, int ktn) {
        const int kk = ktn << 6;                            // 64 k per step
        #pragma unroll
        for (int i = 0; i < 2; ++i) {
            const int chunk = wave * 2 + i;
            #pragma unroll
            for (int sub = 0; sub < 2; ++sub) {
                const short* gA = A + (size_t)(row0 + chunk * 16 + ldr) * 1024 + kk + sub * 32 + lko;
                const short* gW = W + (size_t)(col0 + chunk * 16 + ldr) * 1024 + kk + sub * 32 + lko;
                async_copy16(gA, (char*)AHS(bufi) + sub * 8192 + chunk * 1024);
                async_copy16(gW, (char*)WHS(bufi) + sub * 8192 + chunk * 1024);
            }
        }
    };

    auto compute = [&](int bufi) {
        #pragma unroll
        for (int sub = 0; sub < 2; ++sub) {
            const short* Ah = AHS(bufi) + sub * 4096;
            const short* Wh = WHS(bufi) + sub * 4096;
            f16x8 ah[4], wh[4];
            #pragma unroll
            for (int mi = 0; mi < 4; ++mi)
                ah[mi] = *(const f16x8*)(Ah + (wm * 64 + mi * 16 + (lane & 15)) * 32 + rsl);
            #pragma unroll
            for (int ni = 0; ni < 4; ++ni)
                wh[ni] = *(const f16x8*)(Wh + (wn * 64 + ni * 16 + (lane & 15)) * 32 + rsl);
            #pragma unroll
            for (int mi = 0; mi < 4; ++mi)
                #pragma unroll
                for (int ni = 0; ni < 4; ++ni)
                    acc[mi][ni] = __builtin_amdgcn_mfma_f32_16x16x32_f16(ah[mi], wh[ni], acc[mi][ni], 0, 0, 0);
        }
    };

    // 16 k-steps, 2-buf 1-ahead
    stage(0, 0);
    for (int kt = 0; kt < 14; kt += 2) {
        stage(1, kt + 1);
        VM_WAIT8; SBAR; SCHED0;
        compute(0);
        SBAR;
        stage(0, kt + 2);
        VM_WAIT8; SBAR; SCHED0;
        compute(1);
        SBAR;
    }
    stage(1, 15);
    VM_WAIT8; SBAR; SCHED0;
    compute(0);
    SBAR;
    VM_WAIT0; SBAR; SCHED0;
    compute(1);
    SBAR;   // protect LDS reuse by V-wave transpose below

    // ---- epilogue: write f16 image tiles (+ fused block-mean for q/k)
    const int gr_first = row0 + wm * 64;          // wave's 64-row token block
    const int bb = gr_first >> 11;
    const int mblk = (gr_first & 2047) >> 6;
    const int gc0 = col0 + wn * 64;               // wave's 64-col band (one head)
    const int tsel = gc0 >> 10;
    const int h = (gc0 >> 6) & 15;
    const int tile = ((bb << 4) + h) * 32 + mblk;
    const float sc = (tsel == 0) ? SCALE_F : 1.0f;

    if (tsel != 2) {
        short* baseH = ((tsel == 0) ? QhI : KhI) + (size_t)tile * 4096;
        float* mdst  = ((tsel == 0) ? qbf : kbf) + ((size_t)((bb << 4) + h) * 32 + mblk) * 64;
        #pragma unroll
        for (int ni = 0; ni < 4; ++ni) {
            const int d = ni * 16 + (lane & 15);
            float colsum = 0.f;
            #pragma unroll
            for (int mi = 0; mi < 4; ++mi) {
                #pragma unroll
                for (int r = 0; r < 4; ++r) {
                    const int row = mi * 16 + (lane >> 4) * 4 + r;
                    float v = acc[mi][ni][r] * sc;
                    colsum += v;
                    const int off = (row * 64 + d) ^ ((row & 7) << 3);   // shorts
                    baseH[off] = f16_bits(v);
                }
            }
            colsum += __shfl_xor(colsum, 16);
            colsum += __shfl_xor(colsum, 32);
            if ((lane >> 4) == 0) mdst[d] = colsum * (1.f / 64.f);
        }
    } else {
        // V: transpose 64x64 tile in per-wave LDS region, write Vt[d][kk] image
        short* tb = SM + wave * 4160;   // 64x65 shorts, per-wave exclusive
        #pragma unroll
        for (int ni = 0; ni < 4; ++ni)
            #pragma unroll
            for (int mi = 0; mi < 4; ++mi)
                #pragma unroll
                for (int r = 0; r < 4; ++r) {
                    const int row = mi * 16 + (lane >> 4) * 4 + r;   // kk
                    const int d = ni * 16 + (lane & 15);
                    tb[row * 65 + d] = f16_bits(acc[mi][ni][r]);
                }
        short* vout = VtI + (size_t)tile * 4096;
        #pragma unroll
        for (int c = 0; c < 8; ++c) {
            short8v tv;
            #pragma unroll
            for (int j = 0; j < 8; ++j)
                tv[j] = tb[(c * 8 + j) * 65 + lane];
            const int off = (lane * 64 + c * 8) ^ ((lane & 7) << 3);   // shorts
            *(short8v*)(vout + off) = tv;
        }
    }
}

// Block-scores + top-2 mask (FALLBACK PATH ONLY).
__global__ __launch_bounds__(256) void scores_splitw_kernel(
    const float* __restrict__ qbf, const float* __restrict__ kbf,
    unsigned int* __restrict__ maskbits, float scale,
    const float* __restrict__ projw, short* __restrict__ Wdst)
{
    __shared__ float qs_[32][64];
    __shared__ float ks_[32][64];
    __shared__ float cb[32][32];
    const int bid = blockIdx.x;
    const int tid = threadIdx.x;

    if (bid >= 32) {
        int idx = (bid - 32) * 256 + tid;
        int e = idx * 4;
        float4 v = *(const float4*)(projw + e);
        ushort4 o = make_ushort4((unsigned short)f16_bits(v.x), (unsigned short)f16_bits(v.y),
                                 (unsigned short)f16_bits(v.z), (unsigned short)f16_bits(v.w));
        *(ushort4*)(Wdst + e) = o;
        return;
    }

    #pragma unroll
    for (int i = 0; i < 8; ++i) {
        int e = tid + i * 256;
        qs_[e >> 6][e & 63] = qbf[(size_t)bid * 2048 + e];
        ks_[e >> 6][e & 63] = kbf[(size_t)bid * 2048 + e];
    }
    __syncthreads();

    #pragma unroll
    for (int i = 0; i < 4; ++i) {
        int idx = tid + i * 256;
        int r = idx >> 5, c = idx & 31;
        float s = 0.f;
        #pragma unroll
        for (int d = 0; d < 64; ++d) s += qs_[r][d] * ks_[c][d];
        cb[r][c] = s * scale;
    }
    __syncthreads();

    if (tid < 32) {
        float m1 = -INFINITY, m2 = -INFINITY;
        for (int n = 0; n < 32; ++n) {
            float v = cb[tid][n];
            if (v > m1) { m2 = m1; m1 = v; }
            else if (v > m2) { m2 = v; }
        }
        unsigned int bits = 1u << tid;
        for (int n = 0; n < 32; ++n)
            if (cb[tid][n] >= m2) bits |= 1u << n;
        maskbits[bid * 32 + tid] = bits;
    }
}

// Proj GEMM, f16 single-product + bias — R13 VERBATIM (BK=64, vmcnt(6)).
__global__ __launch_bounds__(256) void proj_mfma_kernel(
    const short* __restrict__ A, const short* __restrict__ W,
    const float* __restrict__ bias, float* __restrict__ out)
{
    __shared__ short Ahs[2][8192];   // 2 subs x 4096
    __shared__ short Whs[2][4096];   // 2 subs x 2048
    const int bid = blockIdx.x;
    const int wg = (bid & 7) * 64 + (bid >> 3);   // bijective (512 % 8 == 0)
    const int row0 = (wg >> 4) * 128;
    const int col0 = (wg & 15) * 64;
    const int tid = threadIdx.x;
    const int lane = tid & 63;
    const int wave = tid >> 6;

    f32x4 acc[2][4];
    const f32x4 zero = {0.f, 0.f, 0.f, 0.f};
    #pragma unroll
    for (int i = 0; i < 2; ++i)
        #pragma unroll
        for (int j = 0; j < 4; ++j) acc[i][j] = zero;

    const int ldr = lane >> 2;
    const int lko = (((lane & 3) ^ ((lane >> 3) & 3))) * 8;
    const int rsl = ((lane >> 4) ^ ((lane >> 1) & 3)) * 8;

    // 6 global_load_lds per wave per call (A: 2 chunks x 2 subs; W: 2 subs)
    auto stage = [&](int bufi, int ktn) {
        const int kk = ktn << 6;
        #pragma unroll
        for (int i = 0; i < 2; ++i) {
            const int chunk = wave * 2 + i;
            #pragma unroll
            for (int sub = 0; sub < 2; ++sub) {
                const short* gA = A + (size_t)(row0 + chunk * 16 + ldr) * 1024 + kk + sub * 32 + lko;
                async_copy16(gA, (char*)&Ahs[bufi][0] + sub * 8192 + chunk * 1024);
            }
        }
        #pragma unroll
        for (int sub = 0; sub < 2; ++sub) {
            const short* gW = W + (size_t)(col0 + wave * 16 + ldr) * 1024 + kk + sub * 32 + lko;
            async_copy16(gW, (char*)&Whs[bufi][0] + sub * 4096 + wave * 1024);
        }
    };

    auto compute = [&](int bufi) {
        #pragma unroll
        for (int sub = 0; sub < 2; ++sub) {
            const short* Ah = &Ahs[bufi][0] + sub * 4096;
            const short* Wh = &Whs[bufi][0] + sub * 2048;
            f16x8 ah[2], wh[4];
            #pragma unroll
            for (int mi = 0; mi < 2; ++mi)
                ah[mi] = *(const f16x8*)(Ah + (wave * 32 + mi * 16 + (lane & 15)) * 32 + rsl);
            #pragma unroll
            for (int ni = 0; ni < 4; ++ni)
                wh[ni] = *(const f16x8*)(Wh + (ni * 16 + (lane & 15)) * 32 + rsl);
            #pragma unroll
            for (int mi = 0; mi < 2; ++mi)
                #pragma unroll
                for (int ni = 0; ni < 4; ++ni)
                    acc[mi][ni] = __builtin_amdgcn_mfma_f32_16x16x32_f16(ah[mi], wh[ni], acc[mi][ni], 0, 0, 0);
        }
    };

    stage(0, 0);
    for (int kt = 0; kt < 14; kt += 2) {
        stage(1, kt + 1);
        VM_WAIT6; SBAR; SCHED0;
        compute(0);
        SBAR;
        stage(0, kt + 2);
        VM_WAIT6; SBAR; SCHED0;
        compute(1);
        SBAR;
    }
    stage(1, 15);
    VM_WAIT6; SBAR; SCHED0;
    compute(0);
    SBAR;
    VM_WAIT0; SBAR; SCHED0;
    compute(1);

    #pragma unroll
    for (int ni = 0; ni < 4; ++ni) {
        int gc = col0 + ni * 16 + (lane & 15);
        float bv = bias[gc];
        #pragma unroll
        for (int mi = 0; mi < 2; ++mi) {
            int gr0 = row0 + wave * 32 + mi * 16 + (lane >> 4) * 4;
            #pragma unroll
            for (int r = 0; r < 4; ++r)
                out[(size_t)(gr0 + r) * 1024 + gc] = acc[mi][ni][r] + bv;
        }
    }
}

// ---------------------------------------------------------------------------
// Sparse block attention — R14 VERBATIM (proven optimum): staged K/V dbuf
// with 1-ahead vmcnt(4), Q in registers, Pb LSTR=64 XOR swizzled, in-kernel
// mask, swapped-operand per-lane softmax. LDS 40 KB -> 4 blocks/CU.
// ---------------------------------------------------------------------------
__global__ __launch_bounds__(256) void sparse_attn_mfma_kernel(
    const short* __restrict__ QhI, const short* __restrict__ KhI,
    const short* __restrict__ VtI,
    const float* __restrict__ qbf, const float* __restrict__ kbf,
    short* __restrict__ aout)
{
    __shared__ f16 Kh[2][4096];               // dbuf
    __shared__ f16 Vt[2][4096];               // dbuf, [d][kk] swizzled
    __shared__ f16 Pb[4096];                  // P[q][kk], LSTR=64, XOR swizzled

    const int bid = blockIdx.x;
    const int wg = (bid & 7) * 128 + (bid >> 3);  // bijective (1024 % 8 == 0)
    const int m  = wg & 31;
    const int bh = wg >> 5;
    const int b  = bh >> 4, h = bh & 15;
    const int tid = threadIdx.x;
    const int lane = tid & 63;
    const int wave = tid >> 6;
    const f32x4 zero = {0.f, 0.f, 0.f, 0.f};

    const int arow = wave * 16 + (lane & 15);
    const int kofs = (lane >> 4) * 8;      // shorts (for Pb)
    const int colb = (lane >> 4) * 16;     // bytes (for swizzled images)
    const int pswz = (arow & 7) << 3;      // Pb XOR (shorts)

    // ---- K/V tile stage: 4 issues/wave (the vmcnt quantum)
    auto stageKV = [&](int bufi, int nb) {
        const size_t t4 = (size_t)(bh * 32 + nb) * 4096;
        const int so = wave * 1024 + lane * 8;
        async_copy16(KhI + t4 + so,       (char*)&Kh[bufi][0] + wave * 2048);
        async_copy16(KhI + t4 + so + 512, (char*)&Kh[bufi][0] + wave * 2048 + 1024);
        async_copy16(VtI + t4 + so,       (char*)&Vt[bufi][0] + wave * 2048);
        async_copy16(VtI + t4 + so + 512, (char*)&Vt[bufi][0] + wave * 2048 + 1024);
    };

    // ---- diagonal tile is ALWAYS in the mask: stage it first
    stageKV(0, m);

    // ---- Q fragment to REGISTERS (same swizzled image offsets)
    f16x8 qreg[2];
    {
        const short* qt = QhI + (size_t)(bh * 32 + m) * 4096;
        #pragma unroll
        for (int c = 0; c < 2; ++c) {
            const int qoff = (arow * 128 + c * 64 + colb) ^ ((arow & 7) << 4);  // bytes
            qreg[c] = *(const f16x8*)((const char*)qt + qoff);
        }
    }

    // ---- in-kernel mask (R11-proven; FP order == old scores kernel).
    // Consuming the youngest mask load drains ALL older VMEM (Q regs + stage),
    // so the loop's vmcnt(4) accounting below is exact.
    unsigned int mask;
    {
        float c = -INFINITY;
        if (lane < 32) {
            const float* qrow = qbf + ((size_t)bh * 32 + m) * 64;
            const float* krow = kbf + ((size_t)bh * 32 + lane) * 64;
            float s = 0.f;
            for (int d = 0; d < 64; ++d) s += qrow[d] * krow[d];
            c = s;
        }
        float m1 = c;
        #pragma unroll
        for (int off = 1; off < 64; off <<= 1) m1 = fmaxf(m1, __shfl_xor(m1, off));
        unsigned long long eq = __ballot(c == m1);
        float cx = (c == m1) ? -INFINITY : c;
        #pragma unroll
        for (int off = 1; off < 64; off <<= 1) cx = fmaxf(cx, __shfl_xor(cx, off));
        float m2 = (__popcll(eq) >= 2) ? m1 : cx;
        unsigned long long ge = __ballot(c >= m2);
        mask = (unsigned int)(ge & 0xffffffffULL) | (1u << m);
    }

    f32x4 o_acc[4];
    float macc_s = -INFINITY, lacc_s = 0.f;   // per-lane: q = wave*16+(lane&15)
    #pragma unroll
    for (int t = 0; t < 4; ++t) o_acc[t] = zero;

    auto computeTile = [&](int bi) {
        const f16* KhB = &Kh[bi][0];
        // ---- QK^T, SWAPPED operands: mfma(K, Q) -> D[k_local][q]
        f32x4 s_acc[4];
        #pragma unroll
        for (int t = 0; t < 4; ++t) s_acc[t] = zero;
        #pragma unroll
        for (int c = 0; c < 2; ++c) {
            #pragma unroll
            for (int t = 0; t < 4; ++t) {
                const int krow = t * 16 + (lane & 15);
                const int koff = (krow * 128 + c * 64 + colb) ^ ((krow & 7) << 4);
                f16x8 bh_ = *(const f16x8*)((const char*)KhB + koff);
                s_acc[t] = __builtin_amdgcn_mfma_f32_16x16x32_f16(bh_, qreg[c], s_acc[t], 0, 0, 0);
            }
        }

        // ---- per-lane online softmax (q = arow)
        float vmax = s_acc[0][0];
        #pragma unroll
        for (int t = 0; t < 4; ++t)
            #pragma unroll
            for (int r = 0; r < 4; ++r) vmax = fmaxf(vmax, s_acc[t][r]);
        vmax = fmaxf(vmax, __shfl_xor(vmax, 16));
        vmax = fmaxf(vmax, __shfl_xor(vmax, 32));
        float mnew = fmaxf(macc_s, vmax);
        float alpha = expf(macc_s - mnew);
        macc_s = mnew;

        float psum = 0.f;
        #pragma unroll
        for (int t = 0; t < 4; ++t) {
            f16x4 pv;
            #pragma unroll
            for (int r = 0; r < 4; ++r) {
                float p = expf(s_acc[t][r] - mnew);
                psum += p;
                pv[r] = (f16)p;
            }
            // k = t*16 + (lane>>4)*4 + r; XOR flips bits 3-5 only (row-local)
            *(f16x4*)(Pb + ((arow * 64 + t * 16 + (lane >> 4) * 4) ^ pswz)) = pv;
        }
        psum += __shfl_xor(psum, 16);
        psum += __shfl_xor(psum, 32);
        lacc_s = lacc_s * alpha + psum;

        float ab[4];
        #pragma unroll
        for (int r = 0; r < 4; ++r) ab[r] = __shfl(alpha, (lane >> 4) * 4 + r);
        #pragma unroll
        for (int t = 0; t < 4; ++t)
            #pragma unroll
            for (int r = 0; r < 4; ++r) o_acc[t][r] *= ab[r];

        // ---- PV (Pb rows wave-private; same XOR on read)
        const f16* VtB = &Vt[bi][0];
        #pragma unroll
        for (int c = 0; c < 2; ++c) {
            f16x8 af = *(const f16x8*)(Pb + ((arow * 64 + c * 32 + kofs) ^ pswz));
            #pragma unroll
            for (int t = 0; t < 4; ++t) {
                const int vrow = t * 16 + (lane & 15);
                const int voff = (vrow * 128 + c * 64 + colb) ^ ((vrow & 7) << 4);
                f16x8 bf = *(const f16x8*)((const char*)VtB + voff);
                o_acc[t] = __builtin_amdgcn_mfma_f32_16x16x32_f16(af, bf, o_acc[t], 0, 0, 0);
            }
        }
    };

    // ---- pipelined masked loop: diagonal first, then set bits ascending.
    unsigned int mm = mask & ~(1u << m);
    int cur = 0;
    for (;;) {
        int nb_nxt = -1;
        if (mm) { nb_nxt = __builtin_ctz(mm); mm &= mm - 1; stageKV(cur ^ 1, nb_nxt); }
        if (nb_nxt >= 0) { VM_WAIT4; } else { VM_WAIT0; }
        SBAR; SCHED0;
        computeTile(cur);
        SBAR;
        if (nb_nxt < 0) break;
        cur ^= 1;
    }

    // ---- epilogue: normalize (broadcast inv to o_acc rows), write f16 out
    float inv_s = (lacc_s > 0.f) ? (1.f / lacc_s) : 0.f;
    float invb[4];
    #pragma unroll
    for (int r = 0; r < 4; ++r) invb[r] = __shfl(inv_s, (lane >> 4) * 4 + r);
    #pragma unroll
    for (int t = 0; t < 4; ++t) {
        int gc = h * 64 + t * 16 + (lane & 15);
        #pragma unroll
        for (int r = 0; r < 4; ++r) {
            int grow = b * NN + m * 64 + wave * 16 + (lane >> 4) * 4 + r;
            float v = o_acc[t][r] * invb[r];
            aout[(size_t)grow * 1024 + gc] = f16_bits(v);
        }
    }
}

// ===========================================================================
// FALLBACK KERNELS (round-2 proven fp32 path)
// ===========================================================================

__global__ __launch_bounds__(256) void block_mean_kernel(
    const float* __restrict__ qf, const float* __restrict__ kf,
    float* __restrict__ qbf, float* __restrict__ kbf)
{
    int idx = blockIdx.x * 256 + threadIdx.x;
    const float* src = (idx < 65536) ? qf : kf;
    float* dst       = (idx < 65536) ? qbf : kbf;
    int e = idx & 65535;
    int d = e & 63;
    int r = e >> 6;
    size_t base = (size_t)r * 4096 + d;
    float s = 0.f;
    #pragma unroll
    for (int i = 0; i < 64; ++i) s += src[base + (size_t)i * 64];
    dst[e] = s * (1.f / 64.f);
}

__global__ __launch_bounds__(256) void qkv_gemm_fb(
    const float* __restrict__ x, const float* __restrict__ w,
    float* __restrict__ qf, float* __restrict__ kf, float* __restrict__ vf)
{
    __shared__ float As[64][33];
    __shared__ float Bs[64][33];
    const int tid = threadIdx.x;
    const int row0 = blockIdx.y * 64;
    const int col0 = blockIdx.x * 64;
    const int ty = tid >> 4, tx = tid & 15;

    float acc[4][4] = {};
    for (int k0 = 0; k0 < 1024; k0 += 32) {
        #pragma unroll
        for (int i = 0; i < 8; ++i) {
            int e = tid + i * 256;
            int r = e >> 5, c = e & 31;
            As[r][c] = x[(size_t)(row0 + r) * 1024 + k0 + c];
            Bs[r][c] = w[(size_t)(col0 + r) * 1024 + k0 + c];
        }
        __syncthreads();
        #pragma unroll
        for (int kk = 0; kk < 32; ++kk) {
            float a[4], bq[4];
            #pragma unroll
            for (int i = 0; i < 4; ++i) a[i] = As[ty * 4 + i][kk];
            #pragma unroll
            for (int j = 0; j < 4; ++j) bq[j] = Bs[tx * 4 + j][kk];
            #pragma unroll
            for (int i = 0; i < 4; ++i)
                #pragma unroll
                for (int j = 0; j < 4; ++j)
                    acc[i][j] += a[i] * bq[j];
        }
        __syncthreads();
    }

    const int tsel = col0 >> 10;
    const int h    = (col0 & 1023) >> 6;
    float* dstbuf = (tsel == 0) ? qf : (tsel == 1) ? kf : vf;
    #pragma unroll
    for (int i = 0; i < 4; ++i) {
        int row = row0 + ty * 4 + i;
        int b   = row >> 11, n = row & 2047;
        size_t rb = ((size_t)(b * HH + h) * NN + n) * HD64;
        #pragma unroll
        for (int j = 0; j < 4; ++j)
            dstbuf[rb + tx * 4 + j] = acc[i][j];
    }
}

__global__ __launch_bounds__(256) void proj_gemm_fb(
    const float* __restrict__ attn, const float* __restrict__ w,
    const float* __restrict__ bias, float* __restrict__ out)
{
    __shared__ float As[64][33];
    __shared__ float Bs[64][33];
    const int tid = threadIdx.x;
    const int row0 = blockIdx.y * 64;
    const int col0 = blockIdx.x * 64;
    const int ty = tid >> 4, tx = tid & 15;

    float acc[4][4] = {};
    for (int k0 = 0; k0 < 1024; k0 += 32) {
        #pragma unroll
        for (int i = 0; i < 8; ++i) {
            int e = tid + i * 256;
            int r = e >> 5, c = e & 31;
            As[r][c] = attn[(size_t)(row0 + r) * 1024 + k0 + c];
            Bs[r][c] = w[(size_t)(col0 + r) * 1024 + k0 + c];
        }
        __syncthreads();
        #pragma unroll
        for (int kk = 0; kk < 32; ++kk) {
            float a[4], bq[4];
            #pragma unroll
            for (int i = 0; i < 4; ++i) a[i] = As[ty * 4 + i][kk];
            #pragma unroll
            for (int j = 0; j < 4; ++j) bq[j] = Bs[tx * 4 + j][kk];
            #pragma unroll
            for (int i = 0; i < 4; ++i)
                #pragma unroll
                for (int j = 0; j < 4; ++j)
                    acc[i][j] += a[i] * bq[j];
        }
        __syncthreads();
    }

    #pragma unroll
    for (int j = 0; j < 4; ++j) {
        int col = col0 + tx * 4 + j;
        float bv = bias[col];
        #pragma unroll
        for (int i = 0; i < 4; ++i) {
            int row = row0 + ty * 4 + i;
            out[(size_t)row * 1024 + col] = acc[i][j] + bv;
        }
    }
}

__global__ __launch_bounds__(256) void sparse_attn_fb(
    const float* __restrict__ qf, const float* __restrict__ kf,
    const float* __restrict__ vf, const unsigned int* __restrict__ maskbits,
    float* __restrict__ attnf)
{
    __shared__ float kbuf[64][64];
    __shared__ float vbuf[64][64];
    __shared__ float sbuf[64][65];
    const int m  = blockIdx.x & 31;
    const int bh = blockIdx.x >> 5;
    const int b  = bh >> 4, h = bh & 15;
    const int t  = threadIdx.x;
    const int qr = t >> 2;
    const int dg = t & 3;
    const int d0 = dg * 16;

    float qreg[16];
    {
        const float* qp = qf + ((size_t)bh * NN + m * 64 + qr) * HD64 + d0;
        #pragma unroll
        for (int j = 0; j < 16; j += 4) {
            float4 v = *(const float4*)(qp + j);
            qreg[j] = v.x; qreg[j+1] = v.y; qreg[j+2] = v.z; qreg[j+3] = v.w;
        }
    }

    const unsigned int mask = maskbits[bh * 32 + m];
    float macc = -INFINITY, lacc = 0.f;
    float oacc[16];
    #pragma unroll
    for (int j = 0; j < 16; ++j) oacc[j] = 0.f;

    for (int nb = 0; nb < 32; ++nb) {
        if (!((mask >> nb) & 1u)) continue;
        __syncthreads();
        {
            const float* gk = kf + ((size_t)bh * NN + nb * 64) * HD64;
            const float* gv = vf + ((size_t)bh * NN + nb * 64) * HD64;
            #pragma unroll
            for (int i = 0; i < 4; ++i) {
                async_copy16(gk + t * 4 + i * 1024, (char*)kbuf + t * 16 + i * 4096);
                async_copy16(gv + t * 4 + i * 1024, (char*)vbuf + t * 16 + i * 4096);
            }
        }
        __syncthreads();

        float bmax = -INFINITY;
        for (int kk = 0; kk < 64; ++kk) {
            float s = 0.f;
            #pragma unroll
            for (int j = 0; j < 16; ++j) s += qreg[j] * kbuf[kk][d0 + j];
            s += __shfl_xor(s, 1);
            s += __shfl_xor(s, 2);
            s *= SCALE_F;
            if (dg == 0) sbuf[qr][kk] = s;
            bmax = fmaxf(bmax, s);
        }
        float mnew  = fmaxf(macc, bmax);
        float alpha = expf(macc - mnew);
        lacc *= alpha;
        #pragma unroll
        for (int j = 0; j < 16; ++j) oacc[j] *= alpha;
        for (int kk = 0; kk < 64; ++kk) {
            float p = expf(sbuf[qr][kk] - mnew);
            lacc += p;
            #pragma unroll
            for (int j = 0; j < 16; ++j) oacc[j] += p * vbuf[kk][d0 + j];
        }
        macc = mnew;
    }

    float inv = (lacc > 0.f) ? (1.f / lacc) : 0.f;
    size_t orow = ((size_t)(b * NN + m * 64 + qr)) * DIMD + h * 64 + d0;
    #pragma unroll
    for (int j = 0; j < 16; ++j) attnf[orow + j] = oacc[j] * inv;
}

// ---------------------------------------------------------------------------
extern "C" void kernel_launch(void* const* d_in, const int* in_sizes, int n_in,
                              void* d_out, int out_size, void* d_ws, size_t ws_size,
                              hipStream_t stream)
{
    const float* x      = (const float*)d_in[0];
    const float* qkv_w  = (const float*)d_in[1];
    const float* proj_w = (const float*)d_in[2];
    const float* proj_b = (const float*)d_in[3];
    float* out = (float*)d_out;

    // Carve (fast path, ~41 MB):
    //   Qh/Kh/Vt images: 3 x 8 MB f16 tiles [1024 tiles][4096 shorts]
    //   qbf/kbf 512K | mask 4K (fallback only)
    //   Axs 8M f16 [4096][1024] (x-split; reused as attention output)
    //   Wqs 6M f16 [3072][1024] | Wp 2M f16 [1024][1024]
    short* QhI = (short*)d_ws;
    short* KhI = QhI + 4194304;
    short* VtI = KhI + 4194304;
    float* qbf = (float*)(VtI + 4194304);
    float* kbf = qbf + 65536;
    unsigned int* maskb = (unsigned int*)(kbf + 65536);
    short* Axs = (short*)(maskb + 1024);
    short* Wqs = Axs + (size_t)4096 * 1024;
    short* Wp  = Wqs + (size_t)3072 * 1024;
    const size_t need_fast = (size_t)((char*)(Wp + (size_t)1024 * 1024) - (char*)d_ws);

    if (ws_size >= need_fast) {
        split_in_fused_kernel<<<8192, 256, 0, stream>>>(x, Axs, qkv_w, Wqs, proj_w, Wp);
        qkv_mfma_kernel<<<768, 256, 0, stream>>>(Axs, Wqs, QhI, KhI, VtI, qbf, kbf);
        sparse_attn_mfma_kernel<<<1024, 256, 0, stream>>>(QhI, KhI, VtI, qbf, kbf, Axs);
        proj_mfma_kernel<<<512, 256, 0, stream>>>(Axs, Wp, proj_b, out);
    } else {
        float* qf2  = (float*)d_ws;
        float* kf2  = qf2 + 4194304;
        float* vf2  = kf2 + 4194304;
        float* qbf2 = vf2 + 4194304;
        float* kbf2 = qbf2 + 65536;
        unsigned int* maskb2 = (unsigned int*)(kbf2 + 65536);
        float* attnf = (float*)(maskb2 + 1024);
        qkv_gemm_fb<<<dim3(48, 64), 256, 0, stream>>>(x, qkv_w, qf2, kf2, vf2);
        block_mean_kernel<<<512, 256, 0, stream>>>(qf2, kf2, qbf2, kbf2);
        scores_splitw_kernel<<<32, 256, 0, stream>>>(qbf2, kbf2, maskb2, SCALE_F,
                                                     (const float*)nullptr, (short*)nullptr);
        sparse_attn_fb<<<1024, 256, 0, stream>>>(qf2, kf2, vf2, maskb2, attnf);
        proj_gemm_fb<<<dim3(16, 64), 256, 0, stream>>>(attnf, proj_w, proj_b, out);
    }
}